// Round 15
// baseline (152.515 us; speedup 1.0000x reference)
//
#include <hip/hip_runtime.h>
#include <hip/hip_bf16.h>

typedef __attribute__((ext_vector_type(8))) short short8;
typedef __attribute__((ext_vector_type(4))) float f32x4;

#define M_   512
#define N_   4096
#define D_   128
#define P_   3584
#define NKV  1024
#define L_   4096
#define H_   32
#define LOG2E 1.44269504088896340736f

__device__ __forceinline__ ushort f2bf(float f) {
  union { float f; unsigned u; } v; v.f = f;
  unsigned r = (v.u + 0x7fffu + ((v.u >> 16) & 1u)) >> 16;
  return (ushort)r;
}
__device__ __forceinline__ float bf2f(ushort u) {
  union { unsigned u; float f; } v; v.u = ((unsigned)u) << 16;
  return v.f;
}
// exp2 via clang builtin -> v_exp_f32 (compiler-managed, not inline asm)
__device__ __forceinline__ float fexp2(float x) {
  return __builtin_amdgcn_exp2f(x);
}
// packed bf16 pair via compiler intrinsic (v_cvt_pk_bf16_f32); low16=a, high16=b
__device__ __forceinline__ unsigned pk2bf(float a, float b) {
  union { __hip_bfloat162 h; unsigned u; } cv;
  cv.h = __float22bfloat162_rn(make_float2(a, b));
  return cv.u;
}

__device__ __forceinline__ void gload_lds16(const void* g, void* l) {
  __builtin_amdgcn_global_load_lds(
      (const __attribute__((address_space(1))) void*)g,
      (__attribute__((address_space(3))) void*)l, 16, 0, 0);
}

// ---------------------------------------------------------------------------
// Kernel PRE: one dispatch = wtrans (blocks 0..6143, the long pole) + xconv
// (blocks 6144..7167). Independent preprocessing (R13-proven arrangement;
// R14 showed adding vconv here is catastrophic — reverted).
// ---------------------------------------------------------------------------
__global__ __launch_bounds__(256) void pre_wx(
    const float* __restrict__ X, ushort* __restrict__ Xs,
    const float* __restrict__ Wq, const float* __restrict__ Wk,
    const float* __restrict__ Wv, ushort* __restrict__ Wt)
{
  __shared__ float T[64][65];
  const int tid = threadIdx.x;

  if (blockIdx.x < 6144) {
    // ---------------- wtrans body (verbatim) ----------------
    int bx = blockIdx.x & 63;
    int by = blockIdx.x >> 6;
    const float* W; int wcols, c0;
    if (by < 64)      { W = Wq; wcols = 4096; c0 = by * 64; }
    else if (by < 80) { W = Wk; wcols = 1024; c0 = (by - 64) * 64; }
    else              { W = Wv; wcols = 1024; c0 = (by - 80) * 64; }
    int orow0 = by * 64;
    int r0 = bx * 64;

    #pragma unroll
    for (int i = 0; i < 4; ++i) {
      int r = i * 16 + (tid >> 4);
      int c4 = tid & 15;
      float4 f = *reinterpret_cast<const float4*>(&W[(size_t)(r0 + r) * wcols + c0 + c4 * 4]);
      T[r][c4 * 4 + 0] = f.x; T[r][c4 * 4 + 1] = f.y;
      T[r][c4 * 4 + 2] = f.z; T[r][c4 * 4 + 3] = f.w;
    }
    __syncthreads();

    #pragma unroll
    for (int i = 0; i < 2; ++i) {
      int j = i * 256 + tid;
      int orr = j >> 3;
      int ch = j & 7;
      short8 s;
      #pragma unroll
      for (int e = 0; e < 8; ++e) s[e] = f2bf(T[ch * 8 + e][orr]);
      int orow = orow0 + orr;
      int dstch = ch ^ (orow & 7);
      *reinterpret_cast<short8*>(&Wt[(size_t)orow * 4096 + r0 + dstch * 8]) = s;
    }
  } else {
    // ---------------- xconv body (verbatim) ----------------
    int g = (blockIdx.x - 6144) * 256 + tid;
    int row = g >> 9;
    int cir = g & 511;
    int grp = cir >> 3, ch = cir & 7;
    const float* src = &X[(size_t)row * 4096 + cir * 8];
    float4 f0 = *reinterpret_cast<const float4*>(src);
    float4 f1 = *reinterpret_cast<const float4*>(src + 4);
    short8 s;
    s[0] = f2bf(f0.x); s[1] = f2bf(f0.y); s[2] = f2bf(f0.z); s[3] = f2bf(f0.w);
    s[4] = f2bf(f1.x); s[5] = f2bf(f1.y); s[6] = f2bf(f1.z); s[7] = f2bf(f1.w);
    int dcol = grp * 64 + ((ch ^ (row & 7)) * 8);
    *reinterpret_cast<short8*>(&Xs[(size_t)row * 4096 + dcol]) = s;
  }
}

// ---------------------------------------------------------------------------
// Kernel C: FUSED dispatch = gemm3 (blocks 0..383) + FAT vconv (384..511).
// Grid = 512 = exactly 2 blocks/CU: each CU gets {2 gemm} or {gemm + vconv
// streamer}. R12's 3584 thin vconv blocks (also 64KB-capped by the smem
// union -> 2/CU) drained through the ~64 gemm-free CUs in ~28 rounds AFTER
// the gemm — the fused 59.5us tail. 128 fat blocks (28 tiles each,
// grid-stride) co-reside for the GEMM's whole duration instead.
// ---------------------------------------------------------------------------
#define GEMM_STAGE(buf, k0g) do {                                             \
    _Pragma("unroll")                                                         \
    for (int i_ = 0; i_ < 4; ++i_) {                                          \
      int blk_ = w * 4 + i_;                                                  \
      gload_lds16(Asrc + (size_t)(blk_ * 8 + (lane >> 3)) * 4096 + (k0g) + (lane & 7) * 8, \
                  &As[buf][blk_ * 512]);                                      \
    }                                                                         \
    _Pragma("unroll")                                                         \
    for (int i_ = 0; i_ < 4; ++i_) {                                          \
      int blk_ = w * 4 + i_;                                                  \
      gload_lds16(Bsrc + (size_t)(blk_ * 8 + (lane >> 3)) * 4096 + (k0g) + (lane & 7) * 8, \
                  &Bs[buf][blk_ * 512]);                                      \
    }                                                                         \
  } while (0)

__global__ __launch_bounds__(256, 2) void qkv_gemm_vconv(
    const ushort* __restrict__ Xs, const ushort* __restrict__ Wt,
    float* __restrict__ pg,
    const float* __restrict__ cacheV, ushort* __restrict__ Vtn)
{
  __shared__ char smem[65536];
  const int tid = threadIdx.x;

  if (blockIdx.x < 384) {
    // ------------------- gemm3 body (verbatim, smem-cast) -------------------
    const int id = blockIdx.x;
    const int bx = id % 48;
    const int by = (id / 48) % 4;
    const int bz = id / 192;
    const int lane = tid & 63, w = tid >> 6;
    const int wr = w >> 1, wc = w & 1;
    const int m0 = by * 128, n0 = bx * 128;
    const int kb0 = bz * 2048;

    ushort (*As)[128 * 64] = reinterpret_cast<ushort(*)[128 * 64]>(smem);
    ushort (*Bs)[128 * 64] = reinterpret_cast<ushort(*)[128 * 64]>(smem + 32768);

    f32x4 acc[4][4];
    #pragma unroll
    for (int m = 0; m < 4; ++m)
      #pragma unroll
      for (int n = 0; n < 4; ++n)
        acc[m][n] = (f32x4){0.f, 0.f, 0.f, 0.f};

    const ushort* Asrc = Xs + (size_t)m0 * 4096;
    const ushort* Bsrc = Wt + (size_t)n0 * 4096;

    GEMM_STAGE(0, kb0);
    __syncthreads();
    int cur = 0;

    for (int kt = 0; kt < 32; ++kt) {
      if (kt + 1 < 32) GEMM_STAGE(cur ^ 1, kb0 + (kt + 1) * 64);
      #pragma unroll
      for (int kk = 0; kk < 2; ++kk) {
        short8 a[4], b[4];
        #pragma unroll
        for (int m = 0; m < 4; ++m) {
          int row = wr * 64 + m * 16 + (lane & 15);
          int ch = (kk * 4 + (lane >> 4)) ^ (row & 7);
          a[m] = *reinterpret_cast<const short8*>(&As[cur][row * 64 + ch * 8]);
        }
        #pragma unroll
        for (int n = 0; n < 4; ++n) {
          int row = wc * 64 + n * 16 + (lane & 15);
          int ch = (kk * 4 + (lane >> 4)) ^ (row & 7);
          b[n] = *reinterpret_cast<const short8*>(&Bs[cur][row * 64 + ch * 8]);
        }
        #pragma unroll
        for (int m = 0; m < 4; ++m)
          #pragma unroll
          for (int n = 0; n < 4; ++n)
            acc[m][n] = __builtin_amdgcn_mfma_f32_16x16x32_bf16(a[m], b[n], acc[m][n], 0, 0, 0);
      }
      __syncthreads();
      cur ^= 1;
    }

    float* dst = pg + (size_t)bz * 512 * 6144;
    #pragma unroll
    for (int m = 0; m < 4; ++m)
      #pragma unroll
      for (int n = 0; n < 4; ++n)
        #pragma unroll
        for (int j = 0; j < 4; ++j) {
          int row = m0 + wr * 64 + m * 16 + (lane >> 4) * 4 + j;
          int col = n0 + wc * 64 + n * 16 + (lane & 15);
          dst[(size_t)row * 6144 + col] = acc[m][n][j];
        }
  } else {
    // -------------- FAT vconv: 28 tiles per block, grid-stride --------------
    // cache_V rows [0,P) -> Vtn bf16 transposed, NATURAL chunk slots,
    // l-interleaved content (chunk cc holds l-local = (cc>>2)*32 +
    // (cc&3)*4 + {0..3, 16..19}, matching attn A k-slots).
    const int id2 = blockIdx.x - 384;   // 0..127
    float (*T)[65] = reinterpret_cast<float(*)[65]>(smem);
    const int r4 = tid >> 4, c = tid & 15;
    const int dr = tid >> 2, part = tid & 3;

    for (int t = id2; t < 3584; t += 128) {
      int h = t & 31;
      int rest = t >> 5;
      int lt = rest % 56;
      int dh = rest / 56;
      int l0 = lt * 64, d0 = dh * 64;

      #pragma unroll
      for (int p = 0; p < 4; ++p) {
        int r = p * 16 + r4;
        float4 f = *reinterpret_cast<const float4*>(
            &cacheV[((size_t)h * L_ + l0 + r) * 128 + d0 + c * 4]);
        T[r][c * 4 + 0] = f.x; T[r][c * 4 + 1] = f.y;
        T[r][c * 4 + 2] = f.z; T[r][c * 4 + 3] = f.w;
      }
      __syncthreads();

      int d = d0 + dr;
      #pragma unroll
      for (int q = 0; q < 2; ++q) {
        int cc = part * 2 + q;
        int half = cc >> 2, c4 = (cc & 3) * 4;
        short8 s;
        #pragma unroll
        for (int e = 0; e < 8; ++e) {
          int lrow = half * 32 + c4 + (e < 4 ? e : 16 + (e - 4));
          s[e] = f2bf(T[lrow][dr]);
        }
        *reinterpret_cast<short8*>(&Vtn[((size_t)h * 128 + d) * (size_t)L_ + l0 + cc * 8]) = s;
      }
      __syncthreads();   // T reused next iteration
    }
  }
}

// ---------------------------------------------------------------------------
// Kernel COMBINE2: one dispatch = combine_qk (blocks 0..1279) + combine_v
// (blocks 1280..1407). Both read pg, no mutual dependency.
// qb is PRE-SCALED by log2(e); Kbn unswizzled rows P..L; Vtn natural chunks
// with l-interleaved content.
// ---------------------------------------------------------------------------
__global__ __launch_bounds__(256) void combine2(
    const float* __restrict__ pg, ushort* __restrict__ qb,
    ushort* __restrict__ Kbn, ushort* __restrict__ Vtn)
{
  __shared__ float T[64][65];
  const int tid = threadIdx.x;

  if (blockIdx.x < 1280) {
    // ---------------- combine_qk body (verbatim) ----------------
    int id = blockIdx.x * 256 + tid;
    int m = id / 640;
    int c8 = (id - m * 640) * 8;
    const float* p0 = pg + (size_t)m * 6144 + c8;
    const float* p1 = p0 + (size_t)512 * 6144;
    if (c8 < 4096) {
      short8 s;
      #pragma unroll
      for (int e = 0; e < 8; ++e) s[e] = f2bf((p0[e] + p1[e]) * LOG2E);
      *reinterpret_cast<short8*>(&qb[(size_t)m * 4096 + c8]) = s;
    } else {
      short8 s;
      #pragma unroll
      for (int e = 0; e < 8; ++e) s[e] = f2bf(p0[e] + p1[e]);
      int o = c8 - 4096;
      int hk = o >> 7, d0 = o & 127;
      #pragma unroll
      for (int g = 0; g < 4; ++g)
        *reinterpret_cast<short8*>(&Kbn[((size_t)(hk * 4 + g) * 512 + m) * 128 + d0]) = s;
    }
  } else {
    // ---------------- combine_v body (verbatim) ----------------
    int bz = blockIdx.x - 1280;
    int mt = bz & 7, hk = (bz >> 3) & 7, dh = bz >> 6;
    int m0 = mt * 64;
    int d0 = dh * 64;
    int colbase = 5120 + hk * 128 + d0;
    int r = tid >> 2, q4 = tid & 3;

    #pragma unroll
    for (int i = 0; i < 4; ++i) {
      int c = (q4 * 4 + i) * 4;
      const float* p0 = pg + (size_t)(m0 + r) * 6144 + colbase + c;
      const float* p1 = p0 + (size_t)512 * 6144;
      float4 a = *reinterpret_cast<const float4*>(p0);
      float4 b = *reinterpret_cast<const float4*>(p1);
      T[r][c + 0] = a.x + b.x; T[r][c + 1] = a.y + b.y;
      T[r][c + 2] = a.z + b.z; T[r][c + 3] = a.w + b.w;
    }
    __syncthreads();

    #pragma unroll
    for (int p = 0; p < 2; ++p) {
      int idx = p * 256 + tid;
      int dloc = idx >> 3, cc = idx & 7;
      int half = cc >> 2, c4 = (cc & 3) * 4;
      short8 s;
      #pragma unroll
      for (int e = 0; e < 8; ++e) {
        int lrow = half * 32 + c4 + (e < 4 ? e : 16 + (e - 4));
        s[e] = f2bf(T[lrow][dloc]);
      }
      int d = d0 + dloc;
      #pragma unroll
      for (int g = 0; g < 4; ++g) {
        int h = hk * 4 + g;
        *reinterpret_cast<short8*>(&Vtn[((size_t)h * 128 + d) * (size_t)L_ + P_ + m0 + cc * 8]) = s;
      }
    }
  }
}

// ---------------------------------------------------------------------------
// Kernel H: GQA attention v15 (proven 54us): 8 waves x 16 q-rows, s-split 4,
// in-register P, fused K fp32->bf16 staging, exp2+pk2bf numerics,
// 4-buffer K/V LDS, T14 schedule (issue t+2, write t+1, compute t).
// ---------------------------------------------------------------------------
#define ATTN_TILE(bufc) do {                                                  \
    const ushort* Ksb = &Ks[bufc][0];                                         \
    const ushort* Vsb = &Vt[bufc][0];                                         \
    f32x4 sc0 = (f32x4){0.f, 0.f, 0.f, 0.f};                                  \
    f32x4 sc1 = (f32x4){0.f, 0.f, 0.f, 0.f};                                  \
    __builtin_amdgcn_s_setprio(1);                                            \
    _Pragma("unroll")                                                         \
    for (int kk = 0; kk < 4; ++kk) {                                          \
      int ch = (kk * 4 + hi) ^ (lo16 & 7);                                    \
      short8 a0 = *reinterpret_cast<const short8*>(&Ksb[lo16 * 128 + ch * 8]); \
      short8 a1 = *reinterpret_cast<const short8*>(&Ksb[(16 + lo16) * 128 + ch * 8]); \
      sc0 = __builtin_amdgcn_mfma_f32_16x16x32_bf16(a0, qreg[kk], sc0, 0, 0, 0); \
      sc1 = __builtin_amdgcn_mfma_f32_16x16x32_bf16(a1, qreg[kk], sc1, 0, 0, 0); \
    }                                                                         \
    __builtin_amdgcn_s_setprio(0);                                            \
    short8 pa;                                                                \
    {                                                                         \
      float e0 = fexp2(sc0[0]); float e1 = fexp2(sc0[1]);                     \
      float e2 = fexp2(sc0[2]); float e3 = fexp2(sc0[3]);                     \
      float f0 = fexp2(sc1[0]); float f1 = fexp2(sc1[1]);                     \
      float f2 = fexp2(sc1[2]); float f3 = fexp2(sc1[3]);                     \
      rs += ((e0 + e1) + (e2 + e3)) + ((f0 + f1) + (f2 + f3));                \
      union { unsigned u[4]; short8 s; } pk_;                                 \
      pk_.u[0] = pk2bf(e0, e1); pk_.u[1] = pk2bf(e2, e3);                     \
      pk_.u[2] = pk2bf(f0, f1); pk_.u[3] = pk2bf(f2, f3);                     \
      pa = pk_.s;                                                             \
    }                                                                         \
    __builtin_amdgcn_s_setprio(1);                                            \
    _Pragma("unroll")                                                         \
    for (int n = 0; n < 8; ++n) {                                             \
      int d = n * 16 + lo16;                                                  \
      int chv = hi ^ ((d >> 1) & 3);                                          \
      short8 bn = *reinterpret_cast<const short8*>(&Vsb[d * 32 + chv * 8]);   \
      o[n] = __builtin_amdgcn_mfma_f32_16x16x32_bf16(pa, bn, o[n], 0, 0, 0);  \
    }                                                                         \
    __builtin_amdgcn_s_setprio(0);                                            \
  } while (0)

#define AISSUE(t_) do {                                                       \
    if (s3 && (t_) >= 16) {                                                   \
      krn = *reinterpret_cast<const short8*>(                                 \
          &KsrcN[(size_t)((t_) * 32 - 512 + klr) * 128 + kc * 8]);            \
    } else {                                                                  \
      const float* kp_ = &Ksrc[(size_t)((t_) * 32 + klr) * 128 + kc * 8];     \
      kr0 = *reinterpret_cast<const float4*>(kp_);                            \
      kr1 = *reinterpret_cast<const float4*>(kp_ + 4);                        \
    }                                                                         \
    vrn = *reinterpret_cast<const short8*>(                                   \
        &VsrcN[(size_t)vd * (size_t)L_ + (t_) * 32 + vc3 * 8]);               \
  } while (0)

#define AWRITE(t_) do {                                                       \
    short8 ks_;                                                               \
    if (s3 && (t_) >= 16) { ks_ = krn; }                                      \
    else {                                                                    \
      union { unsigned u[4]; short8 s; } kk_;                                 \
      kk_.u[0] = pk2bf(kr0.x, kr0.y); kk_.u[1] = pk2bf(kr0.z, kr0.w);         \
      kk_.u[2] = pk2bf(kr1.x, kr1.y); kk_.u[3] = pk2bf(kr1.z, kr1.w);         \
      ks_ = kk_.s;                                                            \
    }                                                                         \
    *reinterpret_cast<short8*>(&Ks[(t_) & 3][klr * 128 + ((kc ^ (klr & 7)) * 8)]) = ks_; \
    *reinterpret_cast<short8*>(&Vt[(t_) & 3][vd * 32 + (((vc3 ^ (vd >> 1)) & 3) * 8)]) = vrn; \
  } while (0)

__global__ __launch_bounds__(512, 4) void gqa_attn15(
    const ushort* __restrict__ qb, const float* __restrict__ cacheK,
    const ushort* __restrict__ Kbn, const ushort* __restrict__ Vtn,
    ushort* __restrict__ pob, float* __restrict__ prs)
{
  const int b = blockIdx.x;
  const int s = b & 3;            // L-split (1024 l each)
  const int j = b >> 2;           // 0..127
  const int qt = j & 3;           // q-tile
  const int h = j >> 2;           // head 0..31
  const int tid = threadIdx.x, lane = tid & 63, w = tid >> 6;   // w: 0..7
  const int lo16 = lane & 15, hi = lane >> 4;

  __shared__ ushort Ks[4][32 * 128];   // 32 KB
  __shared__ ushort Vt[4][128 * 32];   // 32 KB

  short8 qreg[4];
  {
    int qrow = qt * 128 + w * 16 + lo16;
    #pragma unroll
    for (int kk = 0; kk < 4; ++kk)
      qreg[kk] = *reinterpret_cast<const short8*>(
          &qb[(size_t)qrow * 4096 + h * 128 + (kk * 4 + hi) * 8]);
  }

  f32x4 o[8];
  #pragma unroll
  for (int n = 0; n < 8; ++n)
    o[n] = (f32x4){0.f, 0.f, 0.f, 0.f};
  float rs = 0.f;

  // staging maps: K: thread = (l-row, chunk); V: thread = (d, content-chunk)
  const int klr = tid >> 4, kc = tid & 15;
  const int vd = tid >> 2, vc3 = tid & 3;
  const float* Ksrc = cacheK + ((size_t)h * L_ + s * 1024) * 128;
  const ushort* KsrcN = Kbn + (size_t)h * 512 * 128;
  const ushort* VsrcN = Vtn + (size_t)h * 128 * (size_t)L_ + s * 1024;
  const bool s3 = (s == 3);

  float4 kr0, kr1;
  short8 krn, vrn;

  // prologue: tile 0 loaded+written, tile 1 loads in flight
  AISSUE(0);
  AWRITE(0);
  AISSUE(1);
  asm volatile("s_waitcnt lgkmcnt(0)" ::: "memory");
  __builtin_amdgcn_s_barrier();

  for (int t = 0; t < 32; ++t) {
    if (t + 1 < 32) AWRITE(t + 1);   // buf (t+1)&3: last read at tile t-3, safe
    if (t + 2 < 32) AISSUE(t + 2);   // loads hide under TILE(t)
    ATTN_TILE(t & 3);
    asm volatile("s_waitcnt lgkmcnt(0)" ::: "memory");
    __builtin_amdgcn_s_barrier();
  }

  float rsum = rs;
  rsum += __shfl_xor(rsum, 16, 64);
  rsum += __shfl_xor(rsum, 32, 64);

  const size_t pbase = (size_t)(s * 32 + h) * 512;
  #pragma unroll
  for (int n = 0; n < 8; ++n)
    #pragma unroll
    for (int j2 = 0; j2 < 4; ++j2) {
      int row = qt * 128 + w * 16 + hi * 4 + j2;
      pob[(pbase + row) * 128 + n * 16 + lo16] = f2bf(o[n][j2]);
    }
  if (hi == 0) {
    int row = qt * 128 + w * 16 + lo16;
    prs[pbase + row] = rsum;
  }
}

// ---------------------------------------------------------------------------
// Kernel I: out = sum_s pob / sum_s prs   (pob bf16, 4 splits)
// ---------------------------------------------------------------------------
__global__ __launch_bounds__(256) void reduce_out(
    const ushort* __restrict__ pob, const float* __restrict__ prs,
    float* __restrict__ out)
{
  int id = blockIdx.x * 256 + threadIdx.x;
  int m = id >> 10, dq = id & 1023;
  int h = dq >> 5, d4 = dq & 31;
  float4 acc = {0.f, 0.f, 0.f, 0.f};
  float rsum = 0.f;
  #pragma unroll
  for (int s = 0; s < 4; ++s) {
    size_t base = (size_t)(s * 32 + h) * 512 + m;
    ushort4 v = *reinterpret_cast<const ushort4*>(&pob[base * 128 + d4 * 4]);
    acc.x += bf2f(v.x); acc.y += bf2f(v.y); acc.z += bf2f(v.z); acc.w += bf2f(v.w);
    rsum += prs[base];
  }
  float inv = 1.f / rsum;
  float4 r; r.x = acc.x * inv; r.y = acc.y * inv; r.z = acc.z * inv; r.w = acc.w * inv;
  *reinterpret_cast<float4*>(&out[(size_t)m * 4096 + dq * 4]) = r;
}

extern "C" void kernel_launch(void* const* d_in, const int* in_sizes, int n_in,
                              void* d_out, int out_size, void* d_ws, size_t ws_size,
                              hipStream_t stream) {
  const float* X  = (const float*)d_in[0];
  const float* Wq = (const float*)d_in[1];
  const float* Wk = (const float*)d_in[2];
  const float* Wv = (const float*)d_in[3];
  const float* cK = (const float*)d_in[4];
  const float* cV = (const float*)d_in[5];
  float* out = (float*)d_out;

  ushort* qb  = (ushort*)d_ws;                        // [512][4096] bf16 (pre-scaled log2e)
  ushort* Xs  = qb  + (size_t)M_ * N_;                // [512][4096] bf16 pre-swz
  ushort* Kbn = Xs  + (size_t)M_ * N_;                // [32][512][128] bf16 (new K rows, unswz)
  ushort* Vtn = Kbn + (size_t)H_ * 512 * D_;          // [32][128][4096] bf16 natural interleaved
  float*  prs = (float*)(Vtn + (size_t)H_ * D_ * L_); // [4][32][512] f32
  ushort* pob = (ushort*)(prs + 8 * 32 * 512);        // [4][32][512][128] bf16
  ushort* Wt  = pob + (size_t)4 * H_ * 512 * D_;      // [6144][4096] bf16 pre-swz
  float*  pg  = (float*)(Wt + (size_t)6144 * 4096);   // [2][512][6144] f32

  pre_wx<<<7168, 256, 0, stream>>>(X, Xs, Wq, Wk, Wv, Wt);
  qkv_gemm_vconv<<<512, 256, 0, stream>>>(Xs, Wt, pg, cV, Vtn);
  combine2<<<1408, 256, 0, stream>>>(pg, qb, Kbn, Vtn);
  gqa_attn15<<<512, 512, 0, stream>>>(qb, cK, Kbn, Vtn, pob, prs);
  reduce_out<<<2048, 256, 0, stream>>>(pob, prs, out);
}

// Round 16
// 146.730 us; speedup vs baseline: 1.0394x; 1.0394x over previous
//
#include <hip/hip_runtime.h>
#include <hip/hip_bf16.h>

typedef __attribute__((ext_vector_type(8))) short short8;
typedef __attribute__((ext_vector_type(4))) float f32x4;

#define M_   512
#define N_   4096
#define D_   128
#define P_   3584
#define NKV  1024
#define L_   4096
#define H_   32
#define LOG2E 1.44269504088896340736f

__device__ __forceinline__ ushort f2bf(float f) {
  union { float f; unsigned u; } v; v.f = f;
  unsigned r = (v.u + 0x7fffu + ((v.u >> 16) & 1u)) >> 16;
  return (ushort)r;
}
__device__ __forceinline__ float bf2f(ushort u) {
  union { unsigned u; float f; } v; v.u = ((unsigned)u) << 16;
  return v.f;
}
// exp2 via clang builtin -> v_exp_f32 (compiler-managed, not inline asm)
__device__ __forceinline__ float fexp2(float x) {
  return __builtin_amdgcn_exp2f(x);
}
// packed bf16 pair via compiler intrinsic (v_cvt_pk_bf16_f32); low16=a, high16=b
__device__ __forceinline__ unsigned pk2bf(float a, float b) {
  union { __hip_bfloat162 h; unsigned u; } cv;
  cv.h = __float22bfloat162_rn(make_float2(a, b));
  return cv.u;
}

__device__ __forceinline__ void gload_lds16(const void* g, void* l) {
  __builtin_amdgcn_global_load_lds(
      (const __attribute__((address_space(1))) void*)g,
      (__attribute__((address_space(3))) void*)l, 16, 0, 0);
}

// ---------------------------------------------------------------------------
// Kernel PRE: one dispatch = wtrans (blocks 0..6143, the long pole) + xconv
// (blocks 6144..7167). Independent preprocessing; xconv's 8 MB streams under
// wtrans's BW time; one launch gap removed. (R13-proven; ~6.5 TB/s = ceiling.)
// ---------------------------------------------------------------------------
__global__ __launch_bounds__(256) void pre_wx(
    const float* __restrict__ X, ushort* __restrict__ Xs,
    const float* __restrict__ Wq, const float* __restrict__ Wk,
    const float* __restrict__ Wv, ushort* __restrict__ Wt)
{
  __shared__ float T[64][65];
  const int tid = threadIdx.x;

  if (blockIdx.x < 6144) {
    // ---------------- wtrans body (verbatim) ----------------
    int bx = blockIdx.x & 63;
    int by = blockIdx.x >> 6;
    const float* W; int wcols, c0;
    if (by < 64)      { W = Wq; wcols = 4096; c0 = by * 64; }
    else if (by < 80) { W = Wk; wcols = 1024; c0 = (by - 64) * 64; }
    else              { W = Wv; wcols = 1024; c0 = (by - 80) * 64; }
    int orow0 = by * 64;
    int r0 = bx * 64;

    #pragma unroll
    for (int i = 0; i < 4; ++i) {
      int r = i * 16 + (tid >> 4);
      int c4 = tid & 15;
      float4 f = *reinterpret_cast<const float4*>(&W[(size_t)(r0 + r) * wcols + c0 + c4 * 4]);
      T[r][c4 * 4 + 0] = f.x; T[r][c4 * 4 + 1] = f.y;
      T[r][c4 * 4 + 2] = f.z; T[r][c4 * 4 + 3] = f.w;
    }
    __syncthreads();

    #pragma unroll
    for (int i = 0; i < 2; ++i) {
      int j = i * 256 + tid;
      int orr = j >> 3;
      int ch = j & 7;
      short8 s;
      #pragma unroll
      for (int e = 0; e < 8; ++e) s[e] = f2bf(T[ch * 8 + e][orr]);
      int orow = orow0 + orr;
      int dstch = ch ^ (orow & 7);
      *reinterpret_cast<short8*>(&Wt[(size_t)orow * 4096 + r0 + dstch * 8]) = s;
    }
  } else {
    // ---------------- xconv body (verbatim) ----------------
    int g = (blockIdx.x - 6144) * 256 + tid;
    int row = g >> 9;
    int cir = g & 511;
    int grp = cir >> 3, ch = cir & 7;
    const float* src = &X[(size_t)row * 4096 + cir * 8];
    float4 f0 = *reinterpret_cast<const float4*>(src);
    float4 f1 = *reinterpret_cast<const float4*>(src + 4);
    short8 s;
    s[0] = f2bf(f0.x); s[1] = f2bf(f0.y); s[2] = f2bf(f0.z); s[3] = f2bf(f0.w);
    s[4] = f2bf(f1.x); s[5] = f2bf(f1.y); s[6] = f2bf(f1.z); s[7] = f2bf(f1.w);
    int dcol = grp * 64 + ((ch ^ (row & 7)) * 8);
    *reinterpret_cast<short8*>(&Xs[(size_t)row * 4096 + dcol]) = s;
  }
}

// ---------------------------------------------------------------------------
// Kernel C: FUSED dispatch = gemm3 blocks (0..383) + thin vconv (384..3967).
// Measured best-of-four placements for vconv (R12/R13 147.6us): thin blocks
// in the gemm dispatch cost only ~5us over standalone gemm — R15's fat-block
// variant (63-65us) and R14's pre-merge (74.5us) were both worse.
// ---------------------------------------------------------------------------
#define GEMM_STAGE(buf, k0g) do {                                             \
    _Pragma("unroll")                                                         \
    for (int i_ = 0; i_ < 4; ++i_) {                                          \
      int blk_ = w * 4 + i_;                                                  \
      gload_lds16(Asrc + (size_t)(blk_ * 8 + (lane >> 3)) * 4096 + (k0g) + (lane & 7) * 8, \
                  &As[buf][blk_ * 512]);                                      \
    }                                                                         \
    _Pragma("unroll")                                                         \
    for (int i_ = 0; i_ < 4; ++i_) {                                          \
      int blk_ = w * 4 + i_;                                                  \
      gload_lds16(Bsrc + (size_t)(blk_ * 8 + (lane >> 3)) * 4096 + (k0g) + (lane & 7) * 8, \
                  &Bs[buf][blk_ * 512]);                                      \
    }                                                                         \
  } while (0)

__global__ __launch_bounds__(256, 2) void qkv_gemm_vconv(
    const ushort* __restrict__ Xs, const ushort* __restrict__ Wt,
    float* __restrict__ pg,
    const float* __restrict__ cacheV, ushort* __restrict__ Vtn)
{
  __shared__ char smem[65536];
  const int tid = threadIdx.x;

  if (blockIdx.x < 384) {
    // ------------------- gemm3 body (verbatim, smem-cast) -------------------
    const int id = blockIdx.x;
    const int bx = id % 48;
    const int by = (id / 48) % 4;
    const int bz = id / 192;
    const int lane = tid & 63, w = tid >> 6;
    const int wr = w >> 1, wc = w & 1;
    const int m0 = by * 128, n0 = bx * 128;
    const int kb0 = bz * 2048;

    ushort (*As)[128 * 64] = reinterpret_cast<ushort(*)[128 * 64]>(smem);
    ushort (*Bs)[128 * 64] = reinterpret_cast<ushort(*)[128 * 64]>(smem + 32768);

    f32x4 acc[4][4];
    #pragma unroll
    for (int m = 0; m < 4; ++m)
      #pragma unroll
      for (int n = 0; n < 4; ++n)
        acc[m][n] = (f32x4){0.f, 0.f, 0.f, 0.f};

    const ushort* Asrc = Xs + (size_t)m0 * 4096;
    const ushort* Bsrc = Wt + (size_t)n0 * 4096;

    GEMM_STAGE(0, kb0);
    __syncthreads();
    int cur = 0;

    for (int kt = 0; kt < 32; ++kt) {
      if (kt + 1 < 32) GEMM_STAGE(cur ^ 1, kb0 + (kt + 1) * 64);
      #pragma unroll
      for (int kk = 0; kk < 2; ++kk) {
        short8 a[4], b[4];
        #pragma unroll
        for (int m = 0; m < 4; ++m) {
          int row = wr * 64 + m * 16 + (lane & 15);
          int ch = (kk * 4 + (lane >> 4)) ^ (row & 7);
          a[m] = *reinterpret_cast<const short8*>(&As[cur][row * 64 + ch * 8]);
        }
        #pragma unroll
        for (int n = 0; n < 4; ++n) {
          int row = wc * 64 + n * 16 + (lane & 15);
          int ch = (kk * 4 + (lane >> 4)) ^ (row & 7);
          b[n] = *reinterpret_cast<const short8*>(&Bs[cur][row * 64 + ch * 8]);
        }
        #pragma unroll
        for (int m = 0; m < 4; ++m)
          #pragma unroll
          for (int n = 0; n < 4; ++n)
            acc[m][n] = __builtin_amdgcn_mfma_f32_16x16x32_bf16(a[m], b[n], acc[m][n], 0, 0, 0);
      }
      __syncthreads();
      cur ^= 1;
    }

    float* dst = pg + (size_t)bz * 512 * 6144;
    #pragma unroll
    for (int m = 0; m < 4; ++m)
      #pragma unroll
      for (int n = 0; n < 4; ++n)
        #pragma unroll
        for (int j = 0; j < 4; ++j) {
          int row = m0 + wr * 64 + m * 16 + (lane >> 4) * 4 + j;
          int col = n0 + wc * 64 + n * 16 + (lane & 15);
          dst[(size_t)row * 6144 + col] = acc[m][n][j];
        }
  } else {
    // ------------------- vconv body (verbatim, smem-cast) -------------------
    // cache_V rows [0,P) -> Vtn bf16 transposed, NATURAL chunk slots,
    // l-interleaved content (chunk cc holds l-local = (cc>>2)*32 +
    // (cc&3)*4 + {0..3, 16..19}, matching attn A k-slots).
    int id2 = blockIdx.x - 384;
    int h = id2 & 31;
    int rest = id2 >> 5;
    int lt = rest % 56;
    int dh = rest / 56;
    int l0 = lt * 64, d0 = dh * 64;
    float (*T)[65] = reinterpret_cast<float(*)[65]>(smem);
    int r4 = tid >> 4, c = tid & 15;

    #pragma unroll
    for (int p = 0; p < 4; ++p) {
      int r = p * 16 + r4;
      float4 f = *reinterpret_cast<const float4*>(
          &cacheV[((size_t)h * L_ + l0 + r) * 128 + d0 + c * 4]);
      T[r][c * 4 + 0] = f.x; T[r][c * 4 + 1] = f.y;
      T[r][c * 4 + 2] = f.z; T[r][c * 4 + 3] = f.w;
    }
    __syncthreads();

    int dr = tid >> 2, part = tid & 3;
    int d = d0 + dr;
    #pragma unroll
    for (int q = 0; q < 2; ++q) {
      int cc = part * 2 + q;
      int half = cc >> 2, c4 = (cc & 3) * 4;
      short8 s;
      #pragma unroll
      for (int e = 0; e < 8; ++e) {
        int lrow = half * 32 + c4 + (e < 4 ? e : 16 + (e - 4));
        s[e] = f2bf(T[lrow][dr]);
      }
      *reinterpret_cast<short8*>(&Vtn[((size_t)h * 128 + d) * (size_t)L_ + l0 + cc * 8]) = s;
    }
  }
}

// ---------------------------------------------------------------------------
// Kernel COMBINE2: one dispatch = combine_qk (blocks 0..1279) + combine_v
// (blocks 1280..1407). Both read pg, no mutual dependency.
// qb is PRE-SCALED by log2(e); Kbn unswizzled rows P..L; Vtn natural chunks
// with l-interleaved content.
// ---------------------------------------------------------------------------
__global__ __launch_bounds__(256) void combine2(
    const float* __restrict__ pg, ushort* __restrict__ qb,
    ushort* __restrict__ Kbn, ushort* __restrict__ Vtn)
{
  __shared__ float T[64][65];
  const int tid = threadIdx.x;

  if (blockIdx.x < 1280) {
    // ---------------- combine_qk body (verbatim) ----------------
    int id = blockIdx.x * 256 + tid;
    int m = id / 640;
    int c8 = (id - m * 640) * 8;
    const float* p0 = pg + (size_t)m * 6144 + c8;
    const float* p1 = p0 + (size_t)512 * 6144;
    if (c8 < 4096) {
      short8 s;
      #pragma unroll
      for (int e = 0; e < 8; ++e) s[e] = f2bf((p0[e] + p1[e]) * LOG2E);
      *reinterpret_cast<short8*>(&qb[(size_t)m * 4096 + c8]) = s;
    } else {
      short8 s;
      #pragma unroll
      for (int e = 0; e < 8; ++e) s[e] = f2bf(p0[e] + p1[e]);
      int o = c8 - 4096;
      int hk = o >> 7, d0 = o & 127;
      #pragma unroll
      for (int g = 0; g < 4; ++g)
        *reinterpret_cast<short8*>(&Kbn[((size_t)(hk * 4 + g) * 512 + m) * 128 + d0]) = s;
    }
  } else {
    // ---------------- combine_v body (verbatim) ----------------
    int bz = blockIdx.x - 1280;
    int mt = bz & 7, hk = (bz >> 3) & 7, dh = bz >> 6;
    int m0 = mt * 64;
    int d0 = dh * 64;
    int colbase = 5120 + hk * 128 + d0;
    int r = tid >> 2, q4 = tid & 3;

    #pragma unroll
    for (int i = 0; i < 4; ++i) {
      int c = (q4 * 4 + i) * 4;
      const float* p0 = pg + (size_t)(m0 + r) * 6144 + colbase + c;
      const float* p1 = p0 + (size_t)512 * 6144;
      float4 a = *reinterpret_cast<const float4*>(p0);
      float4 b = *reinterpret_cast<const float4*>(p1);
      T[r][c + 0] = a.x + b.x; T[r][c + 1] = a.y + b.y;
      T[r][c + 2] = a.z + b.z; T[r][c + 3] = a.w + b.w;
    }
    __syncthreads();

    #pragma unroll
    for (int p = 0; p < 2; ++p) {
      int idx = p * 256 + tid;
      int dloc = idx >> 3, cc = idx & 7;
      int half = cc >> 2, c4 = (cc & 3) * 4;
      short8 s;
      #pragma unroll
      for (int e = 0; e < 8; ++e) {
        int lrow = half * 32 + c4 + (e < 4 ? e : 16 + (e - 4));
        s[e] = f2bf(T[lrow][dloc]);
      }
      int d = d0 + dloc;
      #pragma unroll
      for (int g = 0; g < 4; ++g) {
        int h = hk * 4 + g;
        *reinterpret_cast<short8*>(&Vtn[((size_t)h * 128 + d) * (size_t)L_ + P_ + m0 + cc * 8]) = s;
      }
    }
  }
}

// ---------------------------------------------------------------------------
// Kernel H: GQA attention v15 (proven 54us): 8 waves x 16 q-rows, s-split 4,
// in-register P, fused K fp32->bf16 staging, exp2+pk2bf numerics,
// 4-buffer K/V LDS, T14 schedule (issue t+2, write t+1, compute t).
// ---------------------------------------------------------------------------
#define ATTN_TILE(bufc) do {                                                  \
    const ushort* Ksb = &Ks[bufc][0];                                         \
    const ushort* Vsb = &Vt[bufc][0];                                         \
    f32x4 sc0 = (f32x4){0.f, 0.f, 0.f, 0.f};                                  \
    f32x4 sc1 = (f32x4){0.f, 0.f, 0.f, 0.f};                                  \
    __builtin_amdgcn_s_setprio(1);                                            \
    _Pragma("unroll")                                                         \
    for (int kk = 0; kk < 4; ++kk) {                                          \
      int ch = (kk * 4 + hi) ^ (lo16 & 7);                                    \
      short8 a0 = *reinterpret_cast<const short8*>(&Ksb[lo16 * 128 + ch * 8]); \
      short8 a1 = *reinterpret_cast<const short8*>(&Ksb[(16 + lo16) * 128 + ch * 8]); \
      sc0 = __builtin_amdgcn_mfma_f32_16x16x32_bf16(a0, qreg[kk], sc0, 0, 0, 0); \
      sc1 = __builtin_amdgcn_mfma_f32_16x16x32_bf16(a1, qreg[kk], sc1, 0, 0, 0); \
    }                                                                         \
    __builtin_amdgcn_s_setprio(0);                                            \
    short8 pa;                                                                \
    {                                                                         \
      float e0 = fexp2(sc0[0]); float e1 = fexp2(sc0[1]);                     \
      float e2 = fexp2(sc0[2]); float e3 = fexp2(sc0[3]);                     \
      float f0 = fexp2(sc1[0]); float f1 = fexp2(sc1[1]);                     \
      float f2 = fexp2(sc1[2]); float f3 = fexp2(sc1[3]);                     \
      rs += ((e0 + e1) + (e2 + e3)) + ((f0 + f1) + (f2 + f3));                \
      union { unsigned u[4]; short8 s; } pk_;                                 \
      pk_.u[0] = pk2bf(e0, e1); pk_.u[1] = pk2bf(e2, e3);                     \
      pk_.u[2] = pk2bf(f0, f1); pk_.u[3] = pk2bf(f2, f3);                     \
      pa = pk_.s;                                                             \
    }                                                                         \
    __builtin_amdgcn_s_setprio(1);                                            \
    _Pragma("unroll")                                                         \
    for (int n = 0; n < 8; ++n) {                                             \
      int d = n * 16 + lo16;                                                  \
      int chv = hi ^ ((d >> 1) & 3);                                          \
      short8 bn = *reinterpret_cast<const short8*>(&Vsb[d * 32 + chv * 8]);   \
      o[n] = __builtin_amdgcn_mfma_f32_16x16x32_bf16(pa, bn, o[n], 0, 0, 0);  \
    }                                                                         \
    __builtin_amdgcn_s_setprio(0);                                            \
  } while (0)

#define AISSUE(t_) do {                                                       \
    if (s3 && (t_) >= 16) {                                                   \
      krn = *reinterpret_cast<const short8*>(                                 \
          &KsrcN[(size_t)((t_) * 32 - 512 + klr) * 128 + kc * 8]);            \
    } else {                                                                  \
      const float* kp_ = &Ksrc[(size_t)((t_) * 32 + klr) * 128 + kc * 8];     \
      kr0 = *reinterpret_cast<const float4*>(kp_);                            \
      kr1 = *reinterpret_cast<const float4*>(kp_ + 4);                        \
    }                                                                         \
    vrn = *reinterpret_cast<const short8*>(                                   \
        &VsrcN[(size_t)vd * (size_t)L_ + (t_) * 32 + vc3 * 8]);               \
  } while (0)

#define AWRITE(t_) do {                                                       \
    short8 ks_;                                                               \
    if (s3 && (t_) >= 16) { ks_ = krn; }                                      \
    else {                                                                    \
      union { unsigned u[4]; short8 s; } kk_;                                 \
      kk_.u[0] = pk2bf(kr0.x, kr0.y); kk_.u[1] = pk2bf(kr0.z, kr0.w);         \
      kk_.u[2] = pk2bf(kr1.x, kr1.y); kk_.u[3] = pk2bf(kr1.z, kr1.w);         \
      ks_ = kk_.s;                                                            \
    }                                                                         \
    *reinterpret_cast<short8*>(&Ks[(t_) & 3][klr * 128 + ((kc ^ (klr & 7)) * 8)]) = ks_; \
    *reinterpret_cast<short8*>(&Vt[(t_) & 3][vd * 32 + (((vc3 ^ (vd >> 1)) & 3) * 8)]) = vrn; \
  } while (0)

__global__ __launch_bounds__(512, 4) void gqa_attn15(
    const ushort* __restrict__ qb, const float* __restrict__ cacheK,
    const ushort* __restrict__ Kbn, const ushort* __restrict__ Vtn,
    ushort* __restrict__ pob, float* __restrict__ prs)
{
  const int b = blockIdx.x;
  const int s = b & 3;            // L-split (1024 l each)
  const int j = b >> 2;           // 0..127
  const int qt = j & 3;           // q-tile
  const int h = j >> 2;           // head 0..31
  const int tid = threadIdx.x, lane = tid & 63, w = tid >> 6;   // w: 0..7
  const int lo16 = lane & 15, hi = lane >> 4;

  __shared__ ushort Ks[4][32 * 128];   // 32 KB
  __shared__ ushort Vt[4][128 * 32];   // 32 KB

  short8 qreg[4];
  {
    int qrow = qt * 128 + w * 16 + lo16;
    #pragma unroll
    for (int kk = 0; kk < 4; ++kk)
      qreg[kk] = *reinterpret_cast<const short8*>(
          &qb[(size_t)qrow * 4096 + h * 128 + (kk * 4 + hi) * 8]);
  }

  f32x4 o[8];
  #pragma unroll
  for (int n = 0; n < 8; ++n)
    o[n] = (f32x4){0.f, 0.f, 0.f, 0.f};
  float rs = 0.f;

  // staging maps: K: thread = (l-row, chunk); V: thread = (d, content-chunk)
  const int klr = tid >> 4, kc = tid & 15;
  const int vd = tid >> 2, vc3 = tid & 3;
  const float* Ksrc = cacheK + ((size_t)h * L_ + s * 1024) * 128;
  const ushort* KsrcN = Kbn + (size_t)h * 512 * 128;
  const ushort* VsrcN = Vtn + (size_t)h * 128 * (size_t)L_ + s * 1024;
  const bool s3 = (s == 3);

  float4 kr0, kr1;
  short8 krn, vrn;

  // prologue: tile 0 loaded+written, tile 1 loads in flight
  AISSUE(0);
  AWRITE(0);
  AISSUE(1);
  asm volatile("s_waitcnt lgkmcnt(0)" ::: "memory");
  __builtin_amdgcn_s_barrier();

  for (int t = 0; t < 32; ++t) {
    if (t + 1 < 32) AWRITE(t + 1);   // buf (t+1)&3: last read at tile t-3, safe
    if (t + 2 < 32) AISSUE(t + 2);   // loads hide under TILE(t)
    ATTN_TILE(t & 3);
    asm volatile("s_waitcnt lgkmcnt(0)" ::: "memory");
    __builtin_amdgcn_s_barrier();
  }

  float rsum = rs;
  rsum += __shfl_xor(rsum, 16, 64);
  rsum += __shfl_xor(rsum, 32, 64);

  const size_t pbase = (size_t)(s * 32 + h) * 512;
  #pragma unroll
  for (int n = 0; n < 8; ++n)
    #pragma unroll
    for (int j2 = 0; j2 < 4; ++j2) {
      int row = qt * 128 + w * 16 + hi * 4 + j2;
      pob[(pbase + row) * 128 + n * 16 + lo16] = f2bf(o[n][j2]);
    }
  if (hi == 0) {
    int row = qt * 128 + w * 16 + lo16;
    prs[pbase + row] = rsum;
  }
}

// ---------------------------------------------------------------------------
// Kernel I: out = sum_s pob / sum_s prs   (pob bf16, 4 splits)
// ---------------------------------------------------------------------------
__global__ __launch_bounds__(256) void reduce_out(
    const ushort* __restrict__ pob, const float* __restrict__ prs,
    float* __restrict__ out)
{
  int id = blockIdx.x * 256 + threadIdx.x;
  int m = id >> 10, dq = id & 1023;
  int h = dq >> 5, d4 = dq & 31;
  float4 acc = {0.f, 0.f, 0.f, 0.f};
  float rsum = 0.f;
  #pragma unroll
  for (int s = 0; s < 4; ++s) {
    size_t base = (size_t)(s * 32 + h) * 512 + m;
    ushort4 v = *reinterpret_cast<const ushort4*>(&pob[base * 128 + d4 * 4]);
    acc.x += bf2f(v.x); acc.y += bf2f(v.y); acc.z += bf2f(v.z); acc.w += bf2f(v.w);
    rsum += prs[base];
  }
  float inv = 1.f / rsum;
  float4 r; r.x = acc.x * inv; r.y = acc.y * inv; r.z = acc.z * inv; r.w = acc.w * inv;
  *reinterpret_cast<float4*>(&out[(size_t)m * 4096 + dq * 4]) = r;
}

extern "C" void kernel_launch(void* const* d_in, const int* in_sizes, int n_in,
                              void* d_out, int out_size, void* d_ws, size_t ws_size,
                              hipStream_t stream) {
  const float* X  = (const float*)d_in[0];
  const float* Wq = (const float*)d_in[1];
  const float* Wk = (const float*)d_in[2];
  const float* Wv = (const float*)d_in[3];
  const float* cK = (const float*)d_in[4];
  const float* cV = (const float*)d_in[5];
  float* out = (float*)d_out;

  ushort* qb  = (ushort*)d_ws;                        // [512][4096] bf16 (pre-scaled log2e)
  ushort* Xs  = qb  + (size_t)M_ * N_;                // [512][4096] bf16 pre-swz
  ushort* Kbn = Xs  + (size_t)M_ * N_;                // [32][512][128] bf16 (new K rows, unswz)
  ushort* Vtn = Kbn + (size_t)H_ * 512 * D_;          // [32][128][4096] bf16 natural interleaved
  float*  prs = (float*)(Vtn + (size_t)H_ * D_ * L_); // [4][32][512] f32
  ushort* pob = (ushort*)(prs + 8 * 32 * 512);        // [4][32][512][128] bf16
  ushort* Wt  = pob + (size_t)4 * H_ * 512 * D_;      // [6144][4096] bf16 pre-swz
  float*  pg  = (float*)(Wt + (size_t)6144 * 4096);   // [2][512][6144] f32

  pre_wx<<<7168, 256, 0, stream>>>(X, Xs, Wq, Wk, Wv, Wt);
  qkv_gemm_vconv<<<3968, 256, 0, stream>>>(Xs, Wt, pg, cV, Vtn);
  combine2<<<1408, 256, 0, stream>>>(pg, qb, Kbn, Vtn);
  gqa_attn15<<<512, 512, 0, stream>>>(qb, cK, Kbn, Vtn, pob, prs);
  reduce_out<<<2048, 256, 0, stream>>>(pob, prs, out);
}